// Round 3
// baseline (385.367 us; speedup 1.0000x reference)
//
#include <hip/hip_runtime.h>
#include <math.h>

#define BATCH 512
#define SEQ   256
#define DIM   256
#define NHEAD 8
#define DFF   1024
#define NT    512   // threads per block
#define NW    8     // waves per block

// ---------- helpers ----------

__device__ __forceinline__ float wave_allred(float v) {
  #pragma unroll
  for (int off = 32; off > 0; off >>= 1) v += __shfl_xor(v, off, 64);
  return v;
}

__device__ __forceinline__ float block_sum(float v, float* red) {
  v = wave_allred(v);
  __syncthreads();
  if ((threadIdx.x & 63) == 0) red[threadIdx.x >> 6] = v;
  __syncthreads();
  float s = 0.f;
  #pragma unroll
  for (int i = 0; i < NW; ++i) s += red[i];
  return s;
}

// one row, K=256: lane covers 4 consecutive floats -> wave covers 1KB contiguous
__device__ __forceinline__ float rowdot256(const float* __restrict__ wrow,
                                           const float* __restrict__ x, int lane) {
  float4 wv = *(const float4*)(wrow + lane * 4);
  float4 xv = *(const float4*)(x + lane * 4);
  float p = fmaf(wv.x, xv.x, fmaf(wv.y, xv.y, fmaf(wv.z, xv.z, wv.w * xv.w)));
  return wave_allred(p);
}

// odd-stride row dot: scalar coalesced sweep j = lane, lane+64, ...
__device__ __forceinline__ float rowdotK(const float* __restrict__ wrow,
                                         const float* __restrict__ x, int K, int lane) {
  float p = 0.f;
  for (int j = lane; j < K; j += 64) p = fmaf(wrow[j], x[j], p);
  return wave_allred(p);
}

// ---------- fused kernel: one block per batch element ----------

__global__ __launch_bounds__(NT, 4) void nmstpp_fused(
    const int*   __restrict__ X,         // (B,S,9)
    const float* __restrict__ emb_act,   // (9,64)
    const float* __restrict__ emb_zone,  // (20,64)
    const float* __restrict__ lin0_w,    // (128,7)
    const float* __restrict__ lin0_b,    // (128)
    const float* __restrict__ qkv_w,     // (768,256)
    const float* __restrict__ qkv_b,     // (768)
    const float* __restrict__ attn_o_w,  // (256,256)
    const float* __restrict__ attn_o_b,  // (256)
    const float* __restrict__ ln1_g, const float* __restrict__ ln1_b,
    const float* __restrict__ ff1_w,     // (1024,256)
    const float* __restrict__ ff1_b,
    const float* __restrict__ ff2_w,     // (256,1024)
    const float* __restrict__ ff2_b,
    const float* __restrict__ ln2_g, const float* __restrict__ ln2_b,
    const float* __restrict__ relu_w,    // (256,256)
    const float* __restrict__ relu_b,
    const float* __restrict__ dT_w,      // (256,256)
    const float* __restrict__ dT_b,
    const float* __restrict__ lindT_w,   // (1,256)
    const float* __restrict__ lindT_b,   // (1)
    const float* __restrict__ zn_w,      // (257,257)
    const float* __restrict__ zn_b,
    const float* __restrict__ linzn_w,   // (20,257)
    const float* __restrict__ linzn_b,
    const float* __restrict__ act0_w,    // (277,277)
    const float* __restrict__ act0_b,
    const float* __restrict__ act1_w,    // (277,277)
    const float* __restrict__ act1_b,
    const float* __restrict__ linact_w,  // (5,277)
    const float* __restrict__ linact_b,
    float* __restrict__ out)             // (B,26)
{
  const int b    = blockIdx.x;
  const int t    = threadIdx.x;
  const int wid  = t >> 6;
  const int lane = t & 63;

  __shared__ alignas(16) float pe_s[SEQ];
  __shared__ alignas(16) float srcl[DIM];
  __shared__ alignas(16) float qv[DIM];      // q -> tv(LN1) -> tv(LN2)
  __shared__ float cb[NHEAD];
  __shared__ alignas(16) float regA[2048];   // w~ [c][h] -> u [h][d]
  __shared__ alignas(16) float sc_s[2048];   // scores [h][s] -> ffb -> z1/a0/a1
  __shared__ alignas(16) float att_s[2048];  // attention [s][h]
  __shared__ alignas(16) float ao_s[DIM];
  __shared__ alignas(16) float h1_s[DIM];    // h1 -> d1
  __shared__ alignas(16) float h2_s[DIM];
  __shared__ alignas(16) float xr_s[DIM];
  __shared__ alignas(16) float fa_s[280];
  __shared__ alignas(16) float znin[260];
  __shared__ float znv[20];
  __shared__ float red[NW];
  __shared__ float embA[9 * 65];
  __shared__ float embZ[20 * 65];
  __shared__ float l0w[128 * 7];
  __shared__ float l0b[128];
  __shared__ int   Xa[SEQ];
  __shared__ int   Xz[SEQ];
  __shared__ float Xo[SEQ * 7];
  __shared__ float scA[9 * 8];
  __shared__ float scZ[20 * 8];
  __shared__ float mHJ[8 * 8];
  __shared__ float biasO8[8];
  __shared__ float wsum8[8];
  __shared__ float attA[8 * 9];
  __shared__ float attZ[8 * 20];
  __shared__ float oAcc[8 * 7];
  __shared__ float peAcc8[8];

  // ---- phase 0: stage tables, X rows, PE row ----
  for (int i = t; i < 9 * 64;  i += NT) embA[(i >> 6) * 65 + (i & 63)] = emb_act[i];
  for (int i = t; i < 20 * 64; i += NT) embZ[(i >> 6) * 65 + (i & 63)] = emb_zone[i];
  for (int i = t; i < 128 * 7; i += NT) l0w[i] = lin0_w[i];
  if (t < 128) l0b[t] = lin0_b[t];
  if (t < SEQ) {
    const int* xrow = X + (b * SEQ + t) * 9;
    Xa[t] = xrow[0];
    Xz[t] = xrow[1];
    #pragma unroll
    for (int j = 0; j < 7; ++j) Xo[t * 7 + j] = (float)xrow[2 + j];
    float ex  = (float)(2 * t) / (float)SEQ;
    float ang = (float)b * exp2f(-ex * 6.643856189774724f);  // 100^-ex
    pe_s[t] = ((t & 1) == 0) ? sinf(ang) : cosf(ang);
  }
  __syncthreads();

  // ---- phase 1: src at last position (channel t) ----
  if (t < DIM) {
    int av = Xa[SEQ - 1], zv = Xz[SEQ - 1];
    float v;
    if (t < 64)        v = embA[av * 65 + t];
    else if (t < 128)  v = embZ[zv * 65 + (t - 64)];
    else {
      const float* lr = l0w + (t - 128) * 7;
      float acc = l0b[t - 128];
      #pragma unroll
      for (int j = 0; j < 7; ++j) acc = fmaf(lr[j], Xo[(SEQ - 1) * 7 + j], acc);
      v = acc;
    }
    srcl[t] = v + pe_s[SEQ - 1];
  }
  __syncthreads();

  // ---- phase 2: q = Wq @ src_last + bq (wave-per-row) ----
  for (int r = wid; r < DIM; r += NW) {
    float s = rowdot256(qkv_w + r * DIM, srcl, lane);
    if (lane == 0) qv[r] = qkv_b[r] + s;
  }
  __syncthreads();

  // ---- phase 3: w~_h[d] (coalesced column sweep; heads split across halves) ----
  {
    const float inv = 0.17677669529663687f;  // 1/sqrt(32)
    const int d = t & 255;
    const int hbase = (t < 256) ? 0 : 4;
    float acc[4] = {0.f, 0.f, 0.f, 0.f};
    for (int c = 0; c < 32; ++c) {
      #pragma unroll
      for (int hh = 0; hh < 4; ++hh) {
        int h = hbase + hh;
        acc[hh] = fmaf(qv[h * 32 + c], qkv_w[(DIM + h * 32 + c) * DIM + d], acc[hh]);
      }
    }
    #pragma unroll
    for (int hh = 0; hh < 4; ++hh) regA[d * 8 + hbase + hh] = acc[hh] * inv;
  }
  __syncthreads();

  // ---- phase 3.5: collapse scores into lookup tables ----
  {
    if (t < 296) {
      int h = t / 37, k = t - h * 37;
      if (k < 9) {
        float acc = 0.f;
        for (int c = 0; c < 64; ++c) acc = fmaf(regA[c * 8 + h], embA[k * 65 + c], acc);
        scA[k * 8 + h] = acc;
      } else if (k < 29) {
        int z = k - 9; float acc = 0.f;
        for (int c = 0; c < 64; ++c) acc = fmaf(regA[(64 + c) * 8 + h], embZ[z * 65 + c], acc);
        scZ[z * 8 + h] = acc;
      } else if (k < 36) {
        int j = k - 29; float acc = 0.f;
        for (int kk = 0; kk < 128; ++kk) acc = fmaf(regA[(128 + kk) * 8 + h], l0w[kk * 7 + j], acc);
        mHJ[h * 8 + j] = acc;
      } else {
        float acc = 0.f;
        for (int c = 0; c < 256; ++c) acc += regA[c * 8 + h];
        wsum8[h] = acc;
      }
    } else if (t < 304) {
      int h = t - 296; float acc = 0.f;
      for (int kk = 0; kk < 128; ++kk) acc = fmaf(regA[(128 + kk) * 8 + h], l0b[kk], acc);
      biasO8[h] = acc;
    } else if (t < 312) {
      int h = t - 304; float acc = 0.f;
      for (int c = 0; c < 32; ++c) acc += qv[h * 32 + c] * qkv_b[DIM + h * 32 + c];
      cb[h] = acc * 0.17677669529663687f;
    }
  }
  __syncthreads();

  // ---- phase 4: scores via tables (thread = position) ----
  if (t < SEQ) {
    const int s = t;
    int av = Xa[s], zv = Xz[s];
    float o[7];
    #pragma unroll
    for (int j = 0; j < 7; ++j) o[j] = Xo[s * 7 + j];
    float pes = pe_s[s];
    #pragma unroll
    for (int h = 0; h < NHEAD; ++h) {
      float acc = scA[av * 8 + h] + scZ[zv * 8 + h] + biasO8[h] + cb[h];
      acc = fmaf(pes, wsum8[h], acc);
      #pragma unroll
      for (int j = 0; j < 7; ++j) acc = fmaf(mHJ[h * 8 + j], o[j], acc);
      sc_s[h * SEQ + s] = acc;
    }
  }
  __syncthreads();

  // ---- phase 5: softmax per head ----
  if (t < 256) {
    const int h = t >> 5, idx = t & 31;
    float vals[8];
    float m = -1e30f;
    #pragma unroll
    for (int i = 0; i < 8; ++i) {
      vals[i] = sc_s[h * SEQ + idx * 8 + i];
      m = fmaxf(m, vals[i]);
    }
    #pragma unroll
    for (int off = 16; off > 0; off >>= 1) m = fmaxf(m, __shfl_xor(m, off, 32));
    float lsum = 0.f;
    #pragma unroll
    for (int i = 0; i < 8; ++i) { vals[i] = expf(vals[i] - m); lsum += vals[i]; }
    #pragma unroll
    for (int off = 16; off > 0; off >>= 1) lsum += __shfl_xor(lsum, off, 32);
    float rinv = 1.0f / lsum;
    #pragma unroll
    for (int i = 0; i < 8; ++i) att_s[(idx * 8 + i) * 8 + h] = vals[i] * rinv;
  }
  __syncthreads();

  // ---- phase 6a: attention-weighted histograms / moments ----
  if (t < 296) {
    int h = t / 37, k = t - h * 37;
    float acc = 0.f;
    if (k < 29) {
      int mybin = (k < 9) ? k : (k - 9);
      const int* bins = (k < 9) ? Xa : Xz;
      for (int s = 0; s < SEQ; ++s) {
        float at = att_s[s * 8 + h];
        acc += (bins[s] == mybin) ? at : 0.f;
      }
      if (k < 9) attA[h * 9 + k] = acc; else attZ[h * 20 + (k - 9)] = acc;
    } else if (k < 36) {
      int j = k - 29;
      for (int s = 0; s < SEQ; ++s) acc = fmaf(att_s[s * 8 + h], Xo[s * 7 + j], acc);
      oAcc[h * 7 + j] = acc;
    } else {
      for (int s = 0; s < SEQ; ++s) acc = fmaf(att_s[s * 8 + h], pe_s[s], acc);
      peAcc8[h] = acc;
    }
  }
  __syncthreads();

  // ---- phase 6b: reconstruct u_h[d] ----
  if (t < DIM) {
    float acc[NHEAD];
    #pragma unroll
    for (int h = 0; h < NHEAD; ++h) acc[h] = peAcc8[h];
    if (t < 64) {
      for (int a = 0; a < 9; ++a) {
        float ev = embA[a * 65 + t];
        #pragma unroll
        for (int h = 0; h < NHEAD; ++h) acc[h] = fmaf(attA[h * 9 + a], ev, acc[h]);
      }
    } else if (t < 128) {
      int d = t - 64;
      for (int z = 0; z < 20; ++z) {
        float ev = embZ[z * 65 + d];
        #pragma unroll
        for (int h = 0; h < NHEAD; ++h) acc[h] = fmaf(attZ[h * 20 + z], ev, acc[h]);
      }
    } else {
      int kk = t - 128;
      #pragma unroll
      for (int j = 0; j < 7; ++j) {
        float ov = l0w[kk * 7 + j];
        #pragma unroll
        for (int h = 0; h < NHEAD; ++h) acc[h] = fmaf(oAcc[h * 7 + j], ov, acc[h]);
      }
      #pragma unroll
      for (int h = 0; h < NHEAD; ++h) acc[h] += l0b[kk];
    }
    #pragma unroll
    for (int h = 0; h < NHEAD; ++h) regA[h * DIM + t] = acc[h];
  }
  __syncthreads();

  // ---- phase 7: ao = Wv @ u + bv (wave-per-row) ----
  for (int r = wid; r < DIM; r += NW) {
    const int h = r >> 5;
    float s = rowdot256(qkv_w + (2 * DIM + r) * DIM, regA + h * DIM, lane);
    if (lane == 0) ao_s[r] = qkv_b[2 * DIM + r] + s;
  }
  __syncthreads();

  // ---- phase 8: tv = src + attn_o(ao); h1 = LN1(tv) ----
  for (int r = wid; r < DIM; r += NW) {
    float s = rowdot256(attn_o_w + r * DIM, ao_s, lane);
    if (lane == 0) qv[r] = srcl[r] + attn_o_b[r] + s;   // qv reused as tv
  }
  __syncthreads();
  {
    float tv = (t < DIM) ? qv[t] : 0.f;
    float mean = block_sum(tv, red) * (1.0f / 256.0f);
    float dv = (t < DIM) ? (tv - mean) : 0.f;
    float var = block_sum(dv * dv, red) * (1.0f / 256.0f);
    if (t < DIM) h1_s[t] = dv / sqrtf(var + 1e-5f) * ln1_g[t] + ln1_b[t];
  }
  __syncthreads();

  // ---- phase 9: f = relu(ff1 @ h1 + b) (wave-per-row, 1024 rows) ----
  for (int r = wid; r < DFF; r += NW) {
    float s = rowdot256(ff1_w + r * DIM, h1_s, lane);
    if (lane == 0) sc_s[r] = fmaxf(ff1_b[r] + s, 0.f);
  }
  __syncthreads();

  // ---- phase 10: tv = h1 + ff2 @ f + b; h2 = LN2(tv) ----
  for (int r = wid; r < DIM; r += NW) {
    const float* row = ff2_w + r * DFF;
    float p = 0.f;
    #pragma unroll
    for (int k = 0; k < 4; ++k) {
      float4 wv = *(const float4*)(row + k * 256 + lane * 4);
      float4 xv = *(const float4*)(sc_s + k * 256 + lane * 4);
      p = fmaf(wv.x, xv.x, fmaf(wv.y, xv.y, fmaf(wv.z, xv.z, fmaf(wv.w, xv.w, p))));
    }
    p = wave_allred(p);
    if (lane == 0) qv[r] = h1_s[r] + ff2_b[r] + p;
  }
  __syncthreads();
  {
    float tv = (t < DIM) ? qv[t] : 0.f;
    float mean = block_sum(tv, red) * (1.0f / 256.0f);
    float dv = (t < DIM) ? (tv - mean) : 0.f;
    float var = block_sum(dv * dv, red) * (1.0f / 256.0f);
    if (t < DIM) h2_s[t] = dv / sqrtf(var + 1e-5f) * ln2_g[t] + ln2_b[t];
  }
  __syncthreads();

  // ---- phase 11: x_relu = relu_w @ h2 + b ----
  for (int r = wid; r < DIM; r += NW) {
    float s = rowdot256(relu_w + r * DIM, h2_s, lane);
    if (lane == 0) xr_s[r] = relu_b[r] + s;
  }
  __syncthreads();

  // ---- phase 12: d1 = dT_w @ x_relu + b; dT = lindT . d1 + b ----
  for (int r = wid; r < DIM; r += NW) {
    float s = rowdot256(dT_w + r * DIM, xr_s, lane);
    if (lane == 0) h1_s[r] = dT_b[r] + s;               // h1_s reused as d1
  }
  __syncthreads();
  float dTv;
  {
    float v = (t < DIM) ? lindT_w[t] * h1_s[t] : 0.f;
    dTv = block_sum(v, red) + lindT_b[0];
  }

  // ---- phase 13: zn path; znin = [dT, x_relu] ----
  if (t < DIM) znin[1 + t] = xr_s[t];
  if (t == 0)  znin[0] = dTv;
  __syncthreads();
  float* z1 = sc_s + 1024;   // 257 floats
  for (int r = wid; r < 257; r += NW) {
    float p = rowdotK(zn_w + r * 257, znin, 257, lane);
    if (lane == 0) z1[r] = zn_b[r] + p;
  }
  if (t < DIM) fa_s[21 + t] = xr_s[t];
  if (t == 256) fa_s[20] = dTv;
  __syncthreads();
  for (int r = wid; r < 20; r += NW) {
    float p = rowdotK(linzn_w + r * 257, z1, 257, lane);
    if (lane == 0) { znv[r] = linzn_b[r] + p; fa_s[r] = linzn_b[r] + p; }
  }
  __syncthreads();

  // ---- phase 14: ac = linact @ act1 @ act0 @ fa ----
  float* a0v = sc_s + 1312;  // 277 floats
  for (int r = wid; r < 277; r += NW) {
    float p = rowdotK(act0_w + r * 277, fa_s, 277, lane);
    if (lane == 0) a0v[r] = act0_b[r] + p;
  }
  __syncthreads();
  float* a1v = sc_s + 1024;  // z1 dead
  for (int r = wid; r < 277; r += NW) {
    float p = rowdotK(act1_w + r * 277, a0v, 277, lane);
    if (lane == 0) a1v[r] = act1_b[r] + p;
  }
  __syncthreads();

  // ---- phase 15: outputs ----
  for (int r = wid; r < 5; r += NW) {
    float p = rowdotK(linact_w + r * 277, a1v, 277, lane);
    if (lane == 0) out[b * 26 + 21 + r] = linact_b[r] + p;
  }
  if (t == 0)  out[b * 26] = dTv;
  if (t < 20)  out[b * 26 + 1 + t] = znv[t];
}

// ---------- launcher ----------

extern "C" void kernel_launch(void* const* d_in, const int* in_sizes, int n_in,
                              void* d_out, int out_size, void* d_ws, size_t ws_size,
                              hipStream_t stream) {
  (void)in_sizes; (void)n_in; (void)d_ws; (void)ws_size; (void)out_size;
  const int*   X        = (const int*)  d_in[0];
  const float* emb_act  = (const float*)d_in[1];
  const float* emb_zone = (const float*)d_in[2];
  const float* lin0_w   = (const float*)d_in[3];
  const float* lin0_b   = (const float*)d_in[4];
  const float* qkv_w    = (const float*)d_in[5];
  const float* qkv_b    = (const float*)d_in[6];
  const float* attn_o_w = (const float*)d_in[7];
  const float* attn_o_b = (const float*)d_in[8];
  const float* ln1_g    = (const float*)d_in[9];
  const float* ln1_b    = (const float*)d_in[10];
  const float* ff1_w    = (const float*)d_in[11];
  const float* ff1_b    = (const float*)d_in[12];
  const float* ff2_w    = (const float*)d_in[13];
  const float* ff2_b    = (const float*)d_in[14];
  const float* ln2_g    = (const float*)d_in[15];
  const float* ln2_b    = (const float*)d_in[16];
  const float* relu_w   = (const float*)d_in[17];
  const float* relu_b   = (const float*)d_in[18];
  const float* dT_w     = (const float*)d_in[19];
  const float* dT_b     = (const float*)d_in[20];
  const float* lindT_w  = (const float*)d_in[21];
  const float* lindT_b  = (const float*)d_in[22];
  const float* zn_w     = (const float*)d_in[23];
  const float* zn_b     = (const float*)d_in[24];
  const float* linzn_w  = (const float*)d_in[25];
  const float* linzn_b  = (const float*)d_in[26];
  const float* act0_w   = (const float*)d_in[27];
  const float* act0_b   = (const float*)d_in[28];
  const float* act1_w   = (const float*)d_in[29];
  const float* act1_b   = (const float*)d_in[30];
  const float* linact_w = (const float*)d_in[31];
  const float* linact_b = (const float*)d_in[32];
  float* out = (float*)d_out;

  nmstpp_fused<<<dim3(BATCH), dim3(NT), 0, stream>>>(
      X, emb_act, emb_zone, lin0_w, lin0_b, qkv_w, qkv_b, attn_o_w, attn_o_b,
      ln1_g, ln1_b, ff1_w, ff1_b, ff2_w, ff2_b, ln2_g, ln2_b,
      relu_w, relu_b, dT_w, dT_b, lindT_w, lindT_b, zn_w, zn_b,
      linzn_w, linzn_b, act0_w, act0_b, act1_w, act1_b, linact_w, linact_b,
      out);
}

// Round 4
// 239.578 us; speedup vs baseline: 1.6085x; 1.6085x over previous
//
#include <hip/hip_runtime.h>
#include <math.h>

#define BATCH 512
#define SEQ   256
#define DIM   256
#define NHEAD 8
#define DFF   1024
#define NT    1024
#define NWAVE 16

// ---------- helpers ----------

__device__ __forceinline__ float dot4f(float4 a, float4 b) {
  return fmaf(a.x, b.x, fmaf(a.y, b.y, fmaf(a.z, b.z, a.w * b.w)));
}

__device__ __forceinline__ float wave_allred(float v) {
  #pragma unroll
  for (int off = 32; off > 0; off >>= 1) v += __shfl_xor(v, off, 64);
  return v;
}

// per-half (batch) block sum; ALL 1024 threads must call
__device__ __forceinline__ float half_sum(float v, float* red) {
  const int tid = threadIdx.x;
  v = wave_allred(v);
  __syncthreads();
  if ((tid & 63) == 0) red[tid >> 6] = v;
  __syncthreads();
  const int base = (tid >= 512) ? 8 : 0;
  float s = 0.f;
  #pragma unroll
  for (int i = 0; i < 8; ++i) s += red[base + i];
  return s;
}

struct BatchBuf {
  float sc[2048];     // w~ [d][h] -> scores [h][s] -> att [s][h] -> u [h][d] -> ffb -> z1/a0/a1
  float pe[SEQ];
  float srcl[DIM];
  float qv[DIM];      // q -> tv(LN1) -> tv(LN2)
  float ao[DIM];
  float h1[DIM];      // h1 -> d1
  float h2[DIM];
  float xr[DIM];
  float znin[260];
  float fa[280];
  float znv[20];
  float cb[8];
  float scA[9 * 8];
  float scZ[20 * 8];
  float mHJ[8 * 8];
  float biasO8[8];
  float wsum8[8];
  float attA[8 * 9];
  float attZ[8 * 20];
  float oAcc[8 * 7];
  float peAcc8[8];
  int   Xa[SEQ];
  int   Xz[SEQ];
  float Xo[SEQ * 7];
};

// ---------- fused kernel: TWO batch elements per block ----------

__global__ __launch_bounds__(NT, 1) void nmstpp_fused(
    const int*   __restrict__ X,
    const float* __restrict__ emb_act,
    const float* __restrict__ emb_zone,
    const float* __restrict__ lin0_w,
    const float* __restrict__ lin0_b,
    const float* __restrict__ qkv_w,
    const float* __restrict__ qkv_b,
    const float* __restrict__ attn_o_w,
    const float* __restrict__ attn_o_b,
    const float* __restrict__ ln1_g, const float* __restrict__ ln1_b,
    const float* __restrict__ ff1_w,
    const float* __restrict__ ff1_b,
    const float* __restrict__ ff2_w,
    const float* __restrict__ ff2_b,
    const float* __restrict__ ln2_g, const float* __restrict__ ln2_b,
    const float* __restrict__ relu_w,
    const float* __restrict__ relu_b,
    const float* __restrict__ dT_w,
    const float* __restrict__ dT_b,
    const float* __restrict__ lindT_w,
    const float* __restrict__ lindT_b,
    const float* __restrict__ zn_w,
    const float* __restrict__ zn_b,
    const float* __restrict__ linzn_w,
    const float* __restrict__ linzn_b,
    const float* __restrict__ act0_w,
    const float* __restrict__ act0_b,
    const float* __restrict__ act1_w,
    const float* __restrict__ act1_b,
    const float* __restrict__ linact_w,
    const float* __restrict__ linact_b,
    float* __restrict__ out)
{
  const int tid   = threadIdx.x;
  const int wid   = tid >> 6;
  const int lane  = tid & 63;
  const int batch = tid >> 9;        // 0 or 1 (half-block)
  const int tp    = tid & 511;       // index within half
  const int b     = 2 * blockIdx.x + batch;

  __shared__ alignas(16) BatchBuf bb[2];
  __shared__ float embA[9 * 65];
  __shared__ float embZ[20 * 65];
  __shared__ float l0w[128 * 7];
  __shared__ float l0b[128];
  __shared__ float red[NWAVE];

  BatchBuf* mb = &bb[batch];         // my half's buffer
  float* sc0 = bb[0].sc;
  float* sc1 = bb[1].sc;

  // ---- phase 0: stage shared tables + per-batch X / pe ----
  for (int i = tid; i < 9 * 64;  i += NT) embA[(i >> 6) * 65 + (i & 63)] = emb_act[i];
  for (int i = tid; i < 20 * 64; i += NT) embZ[(i >> 6) * 65 + (i & 63)] = emb_zone[i];
  for (int i = tid; i < 128 * 7; i += NT) l0w[i] = lin0_w[i];
  if (tid < 128) l0b[tid] = lin0_b[tid];
  if (tp < SEQ) {
    const int* xrow = X + (b * SEQ + tp) * 9;
    mb->Xa[tp] = xrow[0];
    mb->Xz[tp] = xrow[1];
    #pragma unroll
    for (int j = 0; j < 7; ++j) mb->Xo[tp * 7 + j] = (float)xrow[2 + j];
    float ex  = (float)(2 * tp) / (float)SEQ;
    float ang = (float)b * exp2f(-ex * 6.643856189774724f);  // 100^-ex
    mb->pe[tp] = ((tp & 1) == 0) ? sinf(ang) : cosf(ang);
  }
  __syncthreads();

  // ---- phase 1: src at last position ----
  if (tp < DIM) {
    int av = mb->Xa[SEQ - 1], zv = mb->Xz[SEQ - 1];
    float v;
    if (tp < 64)        v = embA[av * 65 + tp];
    else if (tp < 128)  v = embZ[zv * 65 + (tp - 64)];
    else {
      const float* lr = l0w + (tp - 128) * 7;
      float acc = l0b[tp - 128];
      #pragma unroll
      for (int j = 0; j < 7; ++j) acc = fmaf(lr[j], mb->Xo[(SEQ - 1) * 7 + j], acc);
      v = acc;
    }
    mb->srcl[tp] = v + mb->pe[SEQ - 1];
  }
  __syncthreads();

  // ---- phase 2: q = Wq @ srcl + bq (wave-per-row-pair, both batches) ----
  {
    float4 xa0 = *(const float4*)(bb[0].srcl + lane * 4);
    float4 xa1 = *(const float4*)(bb[1].srcl + lane * 4);
    for (int r = wid; r < DIM; r += 32) {
      int r2 = r + 16;
      float4 wa = *(const float4*)(qkv_w + r  * DIM + lane * 4);
      float4 wb = *(const float4*)(qkv_w + r2 * DIM + lane * 4);
      float pa0 = dot4f(wa, xa0), pa1 = dot4f(wa, xa1);
      float pb0 = dot4f(wb, xa0), pb1 = dot4f(wb, xa1);
      #pragma unroll
      for (int off = 32; off > 0; off >>= 1) {
        pa0 += __shfl_xor(pa0, off, 64); pa1 += __shfl_xor(pa1, off, 64);
        pb0 += __shfl_xor(pb0, off, 64); pb1 += __shfl_xor(pb1, off, 64);
      }
      if (lane == 0) {
        bb[0].qv[r]  = qkv_b[r]  + pa0; bb[1].qv[r]  = qkv_b[r]  + pa1;
        bb[0].qv[r2] = qkv_b[r2] + pb0; bb[1].qv[r2] = qkv_b[r2] + pb1;
      }
    }
  }
  __syncthreads();

  // ---- phase 3: w~[d][h] (coalesced column sweep; each half does its batch) ----
  {
    const float inv = 0.17677669529663687f;  // 1/sqrt(32)
    const int d = tp & 255;
    const int hbase = (tp < 256) ? 0 : 4;
    float acc[4] = {0.f, 0.f, 0.f, 0.f};
    for (int c = 0; c < 32; ++c) {
      #pragma unroll
      for (int hh = 0; hh < 4; ++hh) {
        int h = hbase + hh;
        acc[hh] = fmaf(mb->qv[h * 32 + c], qkv_w[(DIM + h * 32 + c) * DIM + d], acc[hh]);
      }
    }
    #pragma unroll
    for (int hh = 0; hh < 4; ++hh) mb->sc[d * 8 + hbase + hh] = acc[hh] * inv;
  }
  __syncthreads();

  // ---- phase 3.5: collapse scores into lookup tables ----
  {
    if (tp < 296) {
      int h = tp / 37, k = tp - h * 37;
      if (k < 9) {
        float acc = 0.f;
        for (int c = 0; c < 64; ++c) acc = fmaf(mb->sc[c * 8 + h], embA[k * 65 + c], acc);
        mb->scA[k * 8 + h] = acc;
      } else if (k < 29) {
        int z = k - 9; float acc = 0.f;
        for (int c = 0; c < 64; ++c) acc = fmaf(mb->sc[(64 + c) * 8 + h], embZ[z * 65 + c], acc);
        mb->scZ[z * 8 + h] = acc;
      } else if (k < 36) {
        int j = k - 29; float acc = 0.f;
        for (int kk = 0; kk < 128; ++kk) acc = fmaf(mb->sc[(128 + kk) * 8 + h], l0w[kk * 7 + j], acc);
        mb->mHJ[h * 8 + j] = acc;
      } else {
        float acc = 0.f;
        for (int c = 0; c < 256; ++c) acc += mb->sc[c * 8 + h];
        mb->wsum8[h] = acc;
      }
    } else if (tp < 304) {
      int h = tp - 296; float acc = 0.f;
      for (int kk = 0; kk < 128; ++kk) acc = fmaf(mb->sc[(128 + kk) * 8 + h], l0b[kk], acc);
      mb->biasO8[h] = acc;
    } else if (tp < 312) {
      int h = tp - 304; float acc = 0.f;
      for (int c = 0; c < 32; ++c) acc += mb->qv[h * 32 + c] * qkv_b[DIM + h * 32 + c];
      mb->cb[h] = acc * 0.17677669529663687f;
    }
  }
  __syncthreads();

  // ---- phase 4: scores via tables (thread = position) ----
  if (tp < SEQ) {
    const int s = tp;
    int av = mb->Xa[s], zv = mb->Xz[s];
    float o[7];
    #pragma unroll
    for (int j = 0; j < 7; ++j) o[j] = mb->Xo[s * 7 + j];
    float pes = mb->pe[s];
    #pragma unroll
    for (int h = 0; h < NHEAD; ++h) {
      float acc = mb->scA[av * 8 + h] + mb->scZ[zv * 8 + h] + mb->biasO8[h] + mb->cb[h];
      acc = fmaf(pes, mb->wsum8[h], acc);
      #pragma unroll
      for (int j = 0; j < 7; ++j) acc = fmaf(mb->mHJ[h * 8 + j], o[j], acc);
      mb->sc[h * SEQ + s] = acc;
    }
  }
  __syncthreads();

  // ---- phase 5: softmax per head, in-place transpose (reg-staged) ----
  {
    float vals[8]; float rinv = 0.f;
    int h = tp >> 5, idx = tp & 31;
    if (tp < 256) {
      float m = -1e30f;
      #pragma unroll
      for (int i = 0; i < 8; ++i) {
        vals[i] = mb->sc[h * SEQ + idx * 8 + i];
        m = fmaxf(m, vals[i]);
      }
      #pragma unroll
      for (int off = 16; off > 0; off >>= 1) m = fmaxf(m, __shfl_xor(m, off, 32));
      float lsum = 0.f;
      #pragma unroll
      for (int i = 0; i < 8; ++i) { vals[i] = expf(vals[i] - m); lsum += vals[i]; }
      #pragma unroll
      for (int off = 16; off > 0; off >>= 1) lsum += __shfl_xor(lsum, off, 32);
      rinv = 1.0f / lsum;
    }
    __syncthreads();
    if (tp < 256) {
      #pragma unroll
      for (int i = 0; i < 8; ++i) mb->sc[(idx * 8 + i) * 8 + h] = vals[i] * rinv;
    }
  }
  __syncthreads();

  // ---- phase 6a: attention-weighted histograms / moments ----
  if (tp < 296) {
    int h = tp / 37, k = tp - h * 37;
    float acc = 0.f;
    if (k < 29) {
      int mybin = (k < 9) ? k : (k - 9);
      const int* bins = (k < 9) ? mb->Xa : mb->Xz;
      for (int s = 0; s < SEQ; ++s) {
        float at = mb->sc[s * 8 + h];
        acc += (bins[s] == mybin) ? at : 0.f;
      }
      if (k < 9) mb->attA[h * 9 + k] = acc; else mb->attZ[h * 20 + (k - 9)] = acc;
    } else if (k < 36) {
      int j = k - 29;
      for (int s = 0; s < SEQ; ++s) acc = fmaf(mb->sc[s * 8 + h], mb->Xo[s * 7 + j], acc);
      mb->oAcc[h * 7 + j] = acc;
    } else {
      for (int s = 0; s < SEQ; ++s) acc = fmaf(mb->sc[s * 8 + h], mb->pe[s], acc);
      mb->peAcc8[h] = acc;
    }
  }
  __syncthreads();

  // ---- phase 6b: reconstruct u[h][d] (overwrites att) ----
  if (tp < DIM) {
    float acc[NHEAD];
    #pragma unroll
    for (int h = 0; h < NHEAD; ++h) acc[h] = mb->peAcc8[h];
    if (tp < 64) {
      for (int a = 0; a < 9; ++a) {
        float ev = embA[a * 65 + tp];
        #pragma unroll
        for (int h = 0; h < NHEAD; ++h) acc[h] = fmaf(mb->attA[h * 9 + a], ev, acc[h]);
      }
    } else if (tp < 128) {
      int d = tp - 64;
      for (int z = 0; z < 20; ++z) {
        float ev = embZ[z * 65 + d];
        #pragma unroll
        for (int h = 0; h < NHEAD; ++h) acc[h] = fmaf(mb->attZ[h * 20 + z], ev, acc[h]);
      }
    } else {
      int kk = tp - 128;
      #pragma unroll
      for (int j = 0; j < 7; ++j) {
        float ov = l0w[kk * 7 + j];
        #pragma unroll
        for (int h = 0; h < NHEAD; ++h) acc[h] = fmaf(mb->oAcc[h * 7 + j], ov, acc[h]);
      }
      #pragma unroll
      for (int h = 0; h < NHEAD; ++h) acc[h] += l0b[kk];
    }
    // NOTE: must not overwrite att before all of 6a done -> 6a/6b separated by barrier
    #pragma unroll
    for (int h = 0; h < NHEAD; ++h) mb->sc[h * DIM + tp] = acc[h];
  }
  __syncthreads();

  // ---- phase 7: ao = Wv @ u + bv ----
  {
    for (int r = wid; r < DIM; r += 32) {
      int r2 = r + 16;
      int h = r >> 5;                       // pair shares head (r&31 = wid < 16)
      float4 xa0 = *(const float4*)(sc0 + h * DIM + lane * 4);
      float4 xa1 = *(const float4*)(sc1 + h * DIM + lane * 4);
      float4 wa = *(const float4*)(qkv_w + (2 * DIM + r)  * DIM + lane * 4);
      float4 wb = *(const float4*)(qkv_w + (2 * DIM + r2) * DIM + lane * 4);
      float pa0 = dot4f(wa, xa0), pa1 = dot4f(wa, xa1);
      float pb0 = dot4f(wb, xa0), pb1 = dot4f(wb, xa1);
      #pragma unroll
      for (int off = 32; off > 0; off >>= 1) {
        pa0 += __shfl_xor(pa0, off, 64); pa1 += __shfl_xor(pa1, off, 64);
        pb0 += __shfl_xor(pb0, off, 64); pb1 += __shfl_xor(pb1, off, 64);
      }
      if (lane == 0) {
        bb[0].ao[r]  = qkv_b[2 * DIM + r]  + pa0; bb[1].ao[r]  = qkv_b[2 * DIM + r]  + pa1;
        bb[0].ao[r2] = qkv_b[2 * DIM + r2] + pb0; bb[1].ao[r2] = qkv_b[2 * DIM + r2] + pb1;
      }
    }
  }
  __syncthreads();

  // ---- phase 8: tv = srcl + attn_o(ao); h1 = LN1(tv) ----
  {
    float4 xa0 = *(const float4*)(bb[0].ao + lane * 4);
    float4 xa1 = *(const float4*)(bb[1].ao + lane * 4);
    for (int r = wid; r < DIM; r += 32) {
      int r2 = r + 16;
      float4 wa = *(const float4*)(attn_o_w + r  * DIM + lane * 4);
      float4 wb = *(const float4*)(attn_o_w + r2 * DIM + lane * 4);
      float pa0 = dot4f(wa, xa0), pa1 = dot4f(wa, xa1);
      float pb0 = dot4f(wb, xa0), pb1 = dot4f(wb, xa1);
      #pragma unroll
      for (int off = 32; off > 0; off >>= 1) {
        pa0 += __shfl_xor(pa0, off, 64); pa1 += __shfl_xor(pa1, off, 64);
        pb0 += __shfl_xor(pb0, off, 64); pb1 += __shfl_xor(pb1, off, 64);
      }
      if (lane == 0) {
        bb[0].qv[r]  = bb[0].srcl[r]  + attn_o_b[r]  + pa0;
        bb[1].qv[r]  = bb[1].srcl[r]  + attn_o_b[r]  + pa1;
        bb[0].qv[r2] = bb[0].srcl[r2] + attn_o_b[r2] + pb0;
        bb[1].qv[r2] = bb[1].srcl[r2] + attn_o_b[r2] + pb1;
      }
    }
  }
  __syncthreads();
  {
    float tv = (tp < DIM) ? mb->qv[tp] : 0.f;
    float mean = half_sum(tv, red) * (1.0f / 256.0f);
    float dv = (tp < DIM) ? (tv - mean) : 0.f;
    float var = half_sum(dv * dv, red) * (1.0f / 256.0f);
    if (tp < DIM) mb->h1[tp] = dv / sqrtf(var + 1e-5f) * ln1_g[tp] + ln1_b[tp];
  }
  __syncthreads();

  // ---- phase 9: ffb = relu(ff1 @ h1 + b) ----
  {
    float4 xa0 = *(const float4*)(bb[0].h1 + lane * 4);
    float4 xa1 = *(const float4*)(bb[1].h1 + lane * 4);
    for (int r = wid; r < DFF; r += 32) {
      int r2 = r + 16;
      float4 wa = *(const float4*)(ff1_w + r  * DIM + lane * 4);
      float4 wb = *(const float4*)(ff1_w + r2 * DIM + lane * 4);
      float pa0 = dot4f(wa, xa0), pa1 = dot4f(wa, xa1);
      float pb0 = dot4f(wb, xa0), pb1 = dot4f(wb, xa1);
      #pragma unroll
      for (int off = 32; off > 0; off >>= 1) {
        pa0 += __shfl_xor(pa0, off, 64); pa1 += __shfl_xor(pa1, off, 64);
        pb0 += __shfl_xor(pb0, off, 64); pb1 += __shfl_xor(pb1, off, 64);
      }
      if (lane == 0) {
        sc0[r]  = fmaxf(ff1_b[r]  + pa0, 0.f); sc1[r]  = fmaxf(ff1_b[r]  + pa1, 0.f);
        sc0[r2] = fmaxf(ff1_b[r2] + pb0, 0.f); sc1[r2] = fmaxf(ff1_b[r2] + pb1, 0.f);
      }
    }
  }
  __syncthreads();

  // ---- phase 10: tv = h1 + ff2 @ ffb + b; h2 = LN2(tv) ----
  {
    for (int r = wid; r < DIM; r += 32) {
      int r2 = r + 16;
      float pa0 = 0.f, pa1 = 0.f, pb0 = 0.f, pb1 = 0.f;
      #pragma unroll
      for (int k = 0; k < 4; ++k) {
        float4 wa  = *(const float4*)(ff2_w + r  * DFF + k * 256 + lane * 4);
        float4 wb  = *(const float4*)(ff2_w + r2 * DFF + k * 256 + lane * 4);
        float4 x0v = *(const float4*)(sc0 + k * 256 + lane * 4);
        float4 x1v = *(const float4*)(sc1 + k * 256 + lane * 4);
        pa0 += dot4f(wa, x0v); pa1 += dot4f(wa, x1v);
        pb0 += dot4f(wb, x0v); pb1 += dot4f(wb, x1v);
      }
      #pragma unroll
      for (int off = 32; off > 0; off >>= 1) {
        pa0 += __shfl_xor(pa0, off, 64); pa1 += __shfl_xor(pa1, off, 64);
        pb0 += __shfl_xor(pb0, off, 64); pb1 += __shfl_xor(pb1, off, 64);
      }
      if (lane == 0) {
        bb[0].qv[r]  = bb[0].h1[r]  + ff2_b[r]  + pa0;
        bb[1].qv[r]  = bb[1].h1[r]  + ff2_b[r]  + pa1;
        bb[0].qv[r2] = bb[0].h1[r2] + ff2_b[r2] + pb0;
        bb[1].qv[r2] = bb[1].h1[r2] + ff2_b[r2] + pb1;
      }
    }
  }
  __syncthreads();
  {
    float tv = (tp < DIM) ? mb->qv[tp] : 0.f;
    float mean = half_sum(tv, red) * (1.0f / 256.0f);
    float dv = (tp < DIM) ? (tv - mean) : 0.f;
    float var = half_sum(dv * dv, red) * (1.0f / 256.0f);
    if (tp < DIM) mb->h2[tp] = dv / sqrtf(var + 1e-5f) * ln2_g[tp] + ln2_b[tp];
  }
  __syncthreads();

  // ---- phase 11: xr = relu_w @ h2 + b ----
  {
    float4 xa0 = *(const float4*)(bb[0].h2 + lane * 4);
    float4 xa1 = *(const float4*)(bb[1].h2 + lane * 4);
    for (int r = wid; r < DIM; r += 32) {
      int r2 = r + 16;
      float4 wa = *(const float4*)(relu_w + r  * DIM + lane * 4);
      float4 wb = *(const float4*)(relu_w + r2 * DIM + lane * 4);
      float pa0 = dot4f(wa, xa0), pa1 = dot4f(wa, xa1);
      float pb0 = dot4f(wb, xa0), pb1 = dot4f(wb, xa1);
      #pragma unroll
      for (int off = 32; off > 0; off >>= 1) {
        pa0 += __shfl_xor(pa0, off, 64); pa1 += __shfl_xor(pa1, off, 64);
        pb0 += __shfl_xor(pb0, off, 64); pb1 += __shfl_xor(pb1, off, 64);
      }
      if (lane == 0) {
        bb[0].xr[r]  = relu_b[r]  + pa0; bb[1].xr[r]  = relu_b[r]  + pa1;
        bb[0].xr[r2] = relu_b[r2] + pb0; bb[1].xr[r2] = relu_b[r2] + pb1;
      }
    }
  }
  __syncthreads();

  // ---- phase 12: d1 = dT_w @ xr + b; dT = lindT . d1 + b ----
  {
    float4 xa0 = *(const float4*)(bb[0].xr + lane * 4);
    float4 xa1 = *(const float4*)(bb[1].xr + lane * 4);
    for (int r = wid; r < DIM; r += 32) {
      int r2 = r + 16;
      float4 wa = *(const float4*)(dT_w + r  * DIM + lane * 4);
      float4 wb = *(const float4*)(dT_w + r2 * DIM + lane * 4);
      float pa0 = dot4f(wa, xa0), pa1 = dot4f(wa, xa1);
      float pb0 = dot4f(wb, xa0), pb1 = dot4f(wb, xa1);
      #pragma unroll
      for (int off = 32; off > 0; off >>= 1) {
        pa0 += __shfl_xor(pa0, off, 64); pa1 += __shfl_xor(pa1, off, 64);
        pb0 += __shfl_xor(pb0, off, 64); pb1 += __shfl_xor(pb1, off, 64);
      }
      if (lane == 0) {
        bb[0].h1[r]  = dT_b[r]  + pa0; bb[1].h1[r]  = dT_b[r]  + pa1;   // h1 = d1
        bb[0].h1[r2] = dT_b[r2] + pb0; bb[1].h1[r2] = dT_b[r2] + pb1;
      }
    }
  }
  __syncthreads();
  float dTv;
  {
    float v = (tp < DIM) ? lindT_w[tp] * mb->h1[tp] : 0.f;
    dTv = half_sum(v, red) + lindT_b[0];
  }

  // ---- phase 13: zn path ----
  if (tp < DIM) { mb->znin[1 + tp] = mb->xr[tp]; mb->fa[21 + tp] = mb->xr[tp]; }
  if (tp == 0)  { mb->znin[0] = dTv; mb->fa[20] = dTv; }
  __syncthreads();
  float* z1_0 = sc0 + 1024; float* z1_1 = sc1 + 1024;
  for (int r = wid; r < 257; r += 16) {
    const float* wr = zn_w + r * 257;
    float p0 = 0.f, p1 = 0.f;
    for (int j = lane; j < 257; j += 64) {
      float w = wr[j];
      p0 = fmaf(w, bb[0].znin[j], p0);
      p1 = fmaf(w, bb[1].znin[j], p1);
    }
    p0 = wave_allred(p0); p1 = wave_allred(p1);
    if (lane == 0) { z1_0[r] = zn_b[r] + p0; z1_1[r] = zn_b[r] + p1; }
  }
  __syncthreads();
  for (int r = wid; r < 20; r += 16) {
    const float* wr = linzn_w + r * 257;
    float p0 = 0.f, p1 = 0.f;
    for (int j = lane; j < 257; j += 64) {
      float w = wr[j];
      p0 = fmaf(w, z1_0[j], p0);
      p1 = fmaf(w, z1_1[j], p1);
    }
    p0 = wave_allred(p0); p1 = wave_allred(p1);
    if (lane == 0) {
      bb[0].znv[r] = linzn_b[r] + p0; bb[0].fa[r] = linzn_b[r] + p0;
      bb[1].znv[r] = linzn_b[r] + p1; bb[1].fa[r] = linzn_b[r] + p1;
    }
  }
  __syncthreads();

  // ---- phase 14: ac = linact @ act1 @ act0 @ fa ----
  float* a0_0 = sc0 + 1312; float* a0_1 = sc1 + 1312;
  for (int r = wid; r < 277; r += 16) {
    const float* wr = act0_w + r * 277;
    float p0 = 0.f, p1 = 0.f;
    for (int j = lane; j < 277; j += 64) {
      float w = wr[j];
      p0 = fmaf(w, bb[0].fa[j], p0);
      p1 = fmaf(w, bb[1].fa[j], p1);
    }
    p0 = wave_allred(p0); p1 = wave_allred(p1);
    if (lane == 0) { a0_0[r] = act0_b[r] + p0; a0_1[r] = act0_b[r] + p1; }
  }
  __syncthreads();
  float* a1_0 = sc0 + 1024; float* a1_1 = sc1 + 1024;  // z1 dead
  for (int r = wid; r < 277; r += 16) {
    const float* wr = act1_w + r * 277;
    float p0 = 0.f, p1 = 0.f;
    for (int j = lane; j < 277; j += 64) {
      float w = wr[j];
      p0 = fmaf(w, a0_0[j], p0);
      p1 = fmaf(w, a0_1[j], p1);
    }
    p0 = wave_allred(p0); p1 = wave_allred(p1);
    if (lane == 0) { a1_0[r] = act1_b[r] + p0; a1_1[r] = act1_b[r] + p1; }
  }
  __syncthreads();

  // ---- phase 15: outputs ----
  for (int r = wid; r < 5; r += 16) {
    const float* wr = linact_w + r * 277;
    float p0 = 0.f, p1 = 0.f;
    for (int j = lane; j < 277; j += 64) {
      float w = wr[j];
      p0 = fmaf(w, a1_0[j], p0);
      p1 = fmaf(w, a1_1[j], p1);
    }
    p0 = wave_allred(p0); p1 = wave_allred(p1);
    if (lane == 0) {
      out[(2 * blockIdx.x)     * 26 + 21 + r] = linact_b[r] + p0;
      out[(2 * blockIdx.x + 1) * 26 + 21 + r] = linact_b[r] + p1;
    }
  }
  if (tp == 0) out[b * 26] = dTv;
  if (tp < 20) out[b * 26 + 1 + tp] = mb->znv[tp];
}

// ---------- launcher ----------

extern "C" void kernel_launch(void* const* d_in, const int* in_sizes, int n_in,
                              void* d_out, int out_size, void* d_ws, size_t ws_size,
                              hipStream_t stream) {
  (void)in_sizes; (void)n_in; (void)d_ws; (void)ws_size; (void)out_size;
  const int*   X        = (const int*)  d_in[0];
  const float* emb_act  = (const float*)d_in[1];
  const float* emb_zone = (const float*)d_in[2];
  const float* lin0_w   = (const float*)d_in[3];
  const float* lin0_b   = (const float*)d_in[4];
  const float* qkv_w    = (const float*)d_in[5];
  const float* qkv_b    = (const float*)d_in[6];
  const float* attn_o_w = (const float*)d_in[7];
  const float* attn_o_b = (const float*)d_in[8];
  const float* ln1_g    = (const float*)d_in[9];
  const float* ln1_b    = (const float*)d_in[10];
  const float* ff1_w    = (const float*)d_in[11];
  const float* ff1_b    = (const float*)d_in[12];
  const float* ff2_w    = (const float*)d_in[13];
  const float* ff2_b    = (const float*)d_in[14];
  const float* ln2_g    = (const float*)d_in[15];
  const float* ln2_b    = (const float*)d_in[16];
  const float* relu_w   = (const float*)d_in[17];
  const float* relu_b   = (const float*)d_in[18];
  const float* dT_w     = (const float*)d_in[19];
  const float* dT_b     = (const float*)d_in[20];
  const float* lindT_w  = (const float*)d_in[21];
  const float* lindT_b  = (const float*)d_in[22];
  const float* zn_w     = (const float*)d_in[23];
  const float* zn_b     = (const float*)d_in[24];
  const float* linzn_w  = (const float*)d_in[25];
  const float* linzn_b  = (const float*)d_in[26];
  const float* act0_w   = (const float*)d_in[27];
  const float* act0_b   = (const float*)d_in[28];
  const float* act1_w   = (const float*)d_in[29];
  const float* act1_b   = (const float*)d_in[30];
  const float* linact_w = (const float*)d_in[31];
  const float* linact_b = (const float*)d_in[32];
  float* out = (float*)d_out;

  nmstpp_fused<<<dim3(BATCH / 2), dim3(NT), 0, stream>>>(
      X, emb_act, emb_zone, lin0_w, lin0_b, qkv_w, qkv_b, attn_o_w, attn_o_b,
      ln1_g, ln1_b, ff1_w, ff1_b, ff2_w, ff2_b, ln2_g, ln2_b,
      relu_w, relu_b, dT_w, dT_b, lindT_w, lindT_b, zn_w, zn_b,
      linzn_w, linzn_b, act0_w, act0_b, act1_w, act1_b, linact_w, linact_b,
      out);
}